// Round 3
// baseline (56.592 us; speedup 1.0000x reference)
//
#include <hip/hip_runtime.h>

typedef float f32x4 __attribute__((ext_vector_type(4)));

#define HH 128
#define WW 192
#define HO 256
#define WO 384
#define NINST 256
#define OTY 64          // output rows per block
#define LTYMAX 34       // low-res rows staged (33 or 34 depending on block)
#define LPAD 196        // row pitch in floats (196*4=784B, 16B aligned, 196%32=4 spreads banks)
#define STRIPS 24       // 192/8 strips per low-res row

__global__ __launch_bounds__(256) void dynmask_fused(
    const float* __restrict__ feats,    // (2, 8, 128, 192)
    const float* __restrict__ params,   // (256, 169)
    const float* __restrict__ locs,     // (256, 2)  [x, y]
    const float* __restrict__ soi,      // (256,)
    const int*   __restrict__ im_inds,  // (256,)
    const int*   __restrict__ stride_p, // (1,)
    float* __restrict__ out)            // (256, 1, 256, 384)
{
    const int n   = blockIdx.y;
    const int t   = threadIdx.x;
    const int oy0 = blockIdx.x * OTY;

    __shared__ float tile[LTYMAX][LPAD];   // 26656 B

    const float sy = 127.0f / 255.0f;
    const float sx = 191.0f / 383.0f;

    const int ly0    = (int)((float)oy0 * sy);
    int lylast       = (int)((float)(oy0 + OTY - 1) * sy) + 1;
    if (lylast > HH - 1) lylast = HH - 1;
    const int lcount = lylast - ly0 + 1;            // 33 or 34

    // wave-uniform -> scalar loads / SGPRs
    const float* __restrict__ pw = params + n * 169;
    const int   stride  = *stride_p;
    const float inv_soi = 1.0f / soi[n];
    const float loc_x   = locs[2*n+0];
    const float loc_y   = locs[2*n+1];
    const float* fbase  = feats + im_inds[n] * (8*HH*WW);

    const float xstep = -(float)stride * inv_soi;

    // ---- MLP over low-res rows [ly0, lylast], strips of 8 px ----
    const int nstrips = lcount * STRIPS;
    for (int s = t; s < nstrips; s += 256) {
        const int r  = s / STRIPS;                  // 0..lcount-1 (no clamp needed)
        const int c0 = (s - r*STRIPS) * 8;
        const int gy = ly0 + r;
        const float* frow = fbase + gy*WW + c0;

        const float yrel = (loc_y - (float)(gy*stride + (stride>>1))) * inv_soi;
        const float xr0  = (loc_x - (float)(c0*stride + (stride>>1))) * inv_soi;

        #pragma unroll
        for (int g = 0; g < 2; ++g) {
            f32x4 f[8];
            #pragma unroll
            for (int ch = 0; ch < 8; ++ch)
                f[ch] = *(const f32x4*)(frow + ch*(HH*WW) + g*4);

            float xr[4];
            #pragma unroll
            for (int j = 0; j < 4; ++j)
                xr[j] = fmaf((float)(g*4+j), xstep, xr0);

            // layer 0: 10 -> 8, relu (weights via SGPR)
            float h0[4][8];
            #pragma unroll
            for (int o = 0; o < 8; ++o) {
                const float wxw = pw[o*10+0];
                const float wyw = pw[o*10+1];
                const float b0w = pw[152+o];
                #pragma unroll
                for (int j = 0; j < 4; ++j) {
                    float a = fmaf(xr[j], wxw, fmaf(yrel, wyw, b0w));
                    #pragma unroll
                    for (int ch = 0; ch < 8; ++ch)
                        a = fmaf(f[ch][j], pw[o*10+2+ch], a);
                    h0[j][o] = fmaxf(a, 0.0f);
                }
            }

            // layers 1+2 fused
            float res[4];
            #pragma unroll
            for (int j = 0; j < 4; ++j) res[j] = pw[168];
            #pragma unroll
            for (int o = 0; o < 8; ++o) {
                const float b1w = pw[160+o];
                const float w2w = pw[144+o];
                #pragma unroll
                for (int j = 0; j < 4; ++j) {
                    float a = b1w;
                    #pragma unroll
                    for (int c = 0; c < 8; ++c)
                        a = fmaf(h0[j][c], pw[80+o*8+c], a);
                    res[j] = fmaf(fmaxf(a, 0.0f), w2w, res[j]);
                }
            }

            f32x4 rv; rv[0]=res[0]; rv[1]=res[1]; rv[2]=res[2]; rv[3]=res[3];
            *(f32x4*)&tile[r][c0 + g*4] = rv;       // 16B aligned (784-byte pitch)
        }
    }

    __syncthreads();

    // ---- bilinear upsample: 64 x 384 outputs, lane owns 4 px strided by 96 ----
    float* obase = out + (size_t)n * (HO*WO);
    #pragma unroll
    for (int k = 0; k < 24; ++k) {
        const int v   = t + k*256;                  // 0..6143
        const int row = (int)((unsigned)v / 96u);   // 0..63
        const int xv  = v - row*96;                 // 0..95
        const int yo  = oy0 + row;

        const float ysf = (float)yo * sy;
        int iy0 = (int)ysf; if (iy0 > HH-2) iy0 = HH-2;
        const float wy = ysf - (float)iy0;
        const float* r0 = tile[iy0 - ly0];
        const float* r1 = tile[iy0 - ly0 + 1];

        float* orow = obase + yo*WO + xv;
        #pragma unroll
        for (int j = 0; j < 4; ++j) {
            const int xo = xv + 96*j;
            const float xsf = (float)xo * sx;
            int ix0 = (int)xsf; if (ix0 > WW-2) ix0 = WW-2;
            const float wxf = xsf - (float)ix0;
            // contiguous pair -> ds_read2_b32
            float a = r0[ix0], b = r0[ix0+1];
            float c = r1[ix0], d = r1[ix0+1];
            float va = fmaf(wy, c - a, a);
            float vb = fmaf(wy, d - b, b);
            orow[96*j] = fmaf(wxf, vb - va, va);
        }
    }
}

extern "C" void kernel_launch(void* const* d_in, const int* in_sizes, int n_in,
                              void* d_out, int out_size, void* d_ws, size_t ws_size,
                              hipStream_t stream) {
    const float* feats    = (const float*)d_in[0];
    const float* params   = (const float*)d_in[1];
    const float* locs     = (const float*)d_in[2];
    const float* soi      = (const float*)d_in[3];
    const int*   im_inds  = (const int*)d_in[4];
    // d_in[5] = fpn_levels (already folded into sizes_of_interest)
    const int*   stride_p = (const int*)d_in[6];
    float* out = (float*)d_out;

    dim3 grid(HO / OTY, NINST);   // (4, 256) = 1024 blocks -> 4 per CU
    dim3 block(256);
    hipLaunchKernelGGL(dynmask_fused, grid, block, 0, stream,
                       feats, params, locs, soi, im_inds, stride_p, out);
}